// Round 3
// baseline (246.246 us; speedup 1.0000x reference)
//
#include <hip/hip_runtime.h>
#include <hip/hip_cooperative_groups.h>

namespace cg = cooperative_groups;

#define MNODES 384
#define RTHRESH 0.05f

// ---------------------------------------------------------------------------
// Single cooperative kernel. Grid = 256 blocks x 384 threads (6 waves/block,
// exactly 1 block/CU). Wave <-> node mapping fixed for the whole kernel:
//   node = blockIdx.x * 6 + wave   (1536 nodes = 4 batches x 384)
// State is carried in registers (s0,s1,s2, wave-uniform). Neighbor lists are
// built once into per-wave LDS (adjacency depends only on x). phi ping-pongs
// between two global buffers in d_ws. 3 grid syncs total:
//   [adj + phi0] S [agg0+g0 -> phi1] S [agg1+g1 -> phi2] S [agg2+g2 -> out]
// Workspace: phiA @ 0 (786432 B), phiB @ 786432 (786432 B).
// ---------------------------------------------------------------------------

__device__ __forceinline__ void phi_stage(
    const float* __restrict__ fW1, const float* __restrict__ fb1,
    const float* __restrict__ fW2, const float* __restrict__ fb2,
    const float* __restrict__ fW3, const float* __restrict__ fb3,
    float s0, float s1, float s2, int lane,
    float* __restrict__ H1, float* __restrict__ H2,
    float* __restrict__ phidst /* this node's 128-float row */)
{
    // Layer 1 (effective 3->64; rel slot of the edge input is exactly zero,
    // so rows 0..2 of fW1 are provably unused)
    float v = fb1[lane];
    v = fmaf(s0, fW1[3 * 64 + lane], v);
    v = fmaf(s1, fW1[4 * 64 + lane], v);
    v = fmaf(s2, fW1[5 * 64 + lane], v);
    H1[lane] = fmaxf(v, 0.0f);
    // Layer 2: 64 -> 128 (same-wave LDS RAW: HW per-wave DS ordering + lgkmcnt)
    float a0 = fb2[lane], a1 = fb2[lane + 64];
#pragma unroll 8
    for (int c = 0; c < 64; ++c) {
        const float h = H1[c];
        a0 = fmaf(h, fW2[c * 128 + lane], a0);
        a1 = fmaf(h, fW2[c * 128 + lane + 64], a1);
    }
    H2[lane] = fmaxf(a0, 0.0f);
    H2[lane + 64] = fmaxf(a1, 0.0f);
    // Layer 3: 128 -> 128, final relu
    float c0 = fb3[lane], c1 = fb3[lane + 64];
#pragma unroll 8
    for (int c = 0; c < 128; ++c) {
        const float h = H2[c];
        c0 = fmaf(h, fW3[c * 128 + lane], c0);
        c1 = fmaf(h, fW3[c * 128 + lane + 64], c1);
    }
    phidst[lane] = fmaxf(c0, 0.0f);
    phidst[lane + 64] = fmaxf(c1, 0.0f);
}

// Max over neighbor phi rows + MLP_g. Returns relu(g3_out) for lanes 0..2.
__device__ __forceinline__ float aggg_stage(
    const float* __restrict__ pb /* phi base for this batch */,
    const unsigned short* __restrict__ nl, int nc,
    const float* __restrict__ gW1, const float* __restrict__ gb1,
    const float* __restrict__ gW2, const float* __restrict__ gb2,
    const float* __restrict__ gW3, const float* __restrict__ gb3,
    int lane, float* __restrict__ aggL, float* __restrict__ h1L,
    float* __restrict__ h2L)
{
    // phi >= 0 and non-neighbors contribute 0 in the reference, so init 0 exact
    float m0 = 0.f, m1 = 0.f, m2 = 0.f, m3 = 0.f;
    float p0 = 0.f, p1 = 0.f, p2 = 0.f, p3 = 0.f;
    int jj = 0;
    for (; jj + 4 <= nc; jj += 4) {
        const int j0 = nl[jj], j1 = nl[jj + 1], j2 = nl[jj + 2], j3 = nl[jj + 3];
        const float* r0 = pb + (size_t)j0 * 128;
        const float* r1 = pb + (size_t)j1 * 128;
        const float* r2 = pb + (size_t)j2 * 128;
        const float* r3 = pb + (size_t)j3 * 128;
        m0 = fmaxf(m0, r0[lane]); p0 = fmaxf(p0, r0[lane + 64]);
        m1 = fmaxf(m1, r1[lane]); p1 = fmaxf(p1, r1[lane + 64]);
        m2 = fmaxf(m2, r2[lane]); p2 = fmaxf(p2, r2[lane + 64]);
        m3 = fmaxf(m3, r3[lane]); p3 = fmaxf(p3, r3[lane + 64]);
    }
    for (; jj < nc; ++jj) {
        const int j = nl[jj];
        const float* r = pb + (size_t)j * 128;
        m0 = fmaxf(m0, r[lane]); p0 = fmaxf(p0, r[lane + 64]);
    }
    aggL[lane] = fmaxf(fmaxf(m0, m1), fmaxf(m2, m3));
    aggL[lane + 64] = fmaxf(fmaxf(p0, p1), fmaxf(p2, p3));
    // g1: 128 -> 64
    float h = gb1[lane];
#pragma unroll 8
    for (int c = 0; c < 128; ++c) h = fmaf(aggL[c], gW1[c * 64 + lane], h);
    h1L[lane] = fmaxf(h, 0.0f);
    // g2: 64 -> 32
    if (lane < 32) {
        float v2 = gb2[lane];
#pragma unroll 8
        for (int k = 0; k < 64; ++k) v2 = fmaf(h1L[k], gW2[k * 32 + lane], v2);
        h2L[lane] = fmaxf(v2, 0.0f);
    }
    // g3: 32 -> 3, final relu
    float o = 0.0f;
    if (lane < 3) {
        float v3 = gb3[lane];
#pragma unroll
        for (int m = 0; m < 32; ++m) v3 = fmaf(h2L[m], gW3[m * 3 + lane], v3);
        o = fmaxf(v3, 0.0f);
    }
    return o;
}

__global__ __launch_bounds__(384) void fused_gnn(
    const float* __restrict__ x,
    const float* __restrict__ fW1, const float* __restrict__ fb1,
    const float* __restrict__ fW2, const float* __restrict__ fb2,
    const float* __restrict__ fW3, const float* __restrict__ fb3,
    const float* __restrict__ gW1, const float* __restrict__ gb1,
    const float* __restrict__ gW2, const float* __restrict__ gb2,
    const float* __restrict__ gW3, const float* __restrict__ gb3,
    float* __restrict__ phiA, float* __restrict__ phiB,
    float* __restrict__ out)
{
    cg::grid_group grid = cg::this_grid();

    __shared__ float xs[MNODES * 3];          // phase-0 batch coords
    __shared__ float work[6][224];            // per-wave scratch (phi: H1|H2, aggg: aggL|h1|h2)
    __shared__ unsigned short nlist[6][384];  // per-wave neighbor list (persists)

    const int tid = threadIdx.x;
    const int wv = tid >> 6, lane = tid & 63;
    const int blk = blockIdx.x;
    const int node = blk * 6 + wv;            // [0,1536)
    const int n = blk >> 6;                   // batch (64 blocks per batch)
    const int i = node - n * MNODES;
    const int nbase = n * MNODES;

    // ---- Phase 0: stage coords, build neighbor list, phi(t=0) -> phiA ----
    for (int idx = tid; idx < MNODES * 3; idx += 384)
        xs[idx] = x[n * MNODES * 3 + idx];
    __syncthreads();

    float s0 = xs[i * 3 + 0], s1 = xs[i * 3 + 1], s2 = xs[i * 3 + 2];  // wave-uniform

    int nc = 0;
    {
        unsigned short* ml = &nlist[wv][0];
#pragma unroll
        for (int rep = 0; rep < 6; ++rep) {
            const int j = rep * 64 + lane;
            float dx = xs[j * 3 + 0] - s0;
            float dy = xs[j * 3 + 1] - s1;
            float dz = xs[j * 3 + 2] - s2;
            // match numpy rounding exactly (no fp-contract): (dx*dx + dy*dy) + dz*dz
            float d2 = __fadd_rn(__fadd_rn(__fmul_rn(dx, dx), __fmul_rn(dy, dy)),
                                 __fmul_rn(dz, dz));
            const bool a = d2 < RTHRESH;
            const unsigned long long m = __ballot(a);
            if (a) ml[nc + __popcll(m & ((1ull << lane) - 1ull))] = (unsigned short)j;
            nc += (int)__popcll(m);
        }
    }

    float* const H1 = &work[wv][0];
    float* const H2 = &work[wv][64];
    phi_stage(fW1, fb1, fW2, fb2, fW3, fb3, s0, s1, s2, lane, H1, H2,
              phiA + (size_t)node * 128);
    grid.sync();

    // ---- Phases 1..3: aggg(t) [+ phi(t+1)] ----
    for (int t = 0; t < 3; ++t) {
        const float* psrc = (t & 1) ? phiB : phiA;
        const float o = aggg_stage(psrc + (size_t)nbase * 128, &nlist[wv][0], nc,
                                   gW1 + t * 8192, gb1 + t * 64,
                                   gW2 + t * 2048, gb2 + t * 32,
                                   gW3 + t * 96, gb3 + t * 3,
                                   lane, &work[wv][0], &work[wv][128], &work[wv][192]);
        const float ns = o + ((lane == 0) ? s0 : (lane == 1) ? s1 : s2);
        s0 = __shfl(ns, 0); s1 = __shfl(ns, 1); s2 = __shfl(ns, 2);
        if (t == 2) {
            if (lane < 3) out[node * 3 + lane] = ns;
        } else {
            const int tn = t + 1;
            float* pdst = (tn & 1) ? phiB : phiA;
            phi_stage(fW1 + tn * 384, fb1 + tn * 64,
                      fW2 + tn * 8192, fb2 + tn * 128,
                      fW3 + tn * 16384, fb3 + tn * 128,
                      s0, s1, s2, lane, H1, H2, pdst + (size_t)node * 128);
            grid.sync();
        }
    }
}

extern "C" void kernel_launch(void* const* d_in, const int* in_sizes, int n_in,
                              void* d_out, int out_size, void* d_ws, size_t ws_size,
                              hipStream_t stream) {
    const float* x   = (const float*)d_in[0];
    // d_in[1..6] = hW1..hb3 : provably unused (delta MLP receives exact zeros)
    const float* fW1 = (const float*)d_in[7];
    const float* fb1 = (const float*)d_in[8];
    const float* fW2 = (const float*)d_in[9];
    const float* fb2 = (const float*)d_in[10];
    const float* fW3 = (const float*)d_in[11];
    const float* fb3 = (const float*)d_in[12];
    const float* gW1 = (const float*)d_in[13];
    const float* gb1 = (const float*)d_in[14];
    const float* gW2 = (const float*)d_in[15];
    const float* gb2 = (const float*)d_in[16];
    const float* gW3 = (const float*)d_in[17];
    const float* gb3 = (const float*)d_in[18];

    float* phiA = (float*)d_ws;
    float* phiB = (float*)((char*)d_ws + 786432);
    float* outp = (float*)d_out;

    void* args[] = {
        (void*)&x,
        (void*)&fW1, (void*)&fb1, (void*)&fW2, (void*)&fb2, (void*)&fW3, (void*)&fb3,
        (void*)&gW1, (void*)&gb1, (void*)&gW2, (void*)&gb2, (void*)&gW3, (void*)&gb3,
        (void*)&phiA, (void*)&phiB, (void*)&outp
    };
    hipLaunchCooperativeKernel((const void*)fused_gnn, dim3(256), dim3(384),
                               args, 0, stream);
}

// Round 4
// 133.836 us; speedup vs baseline: 1.8399x; 1.8399x over previous
//
#include <hip/hip_runtime.h>

#define MNODES 384
#define RTHRESH 0.05f

// ---------------------------------------------------------------------------
// 4 plain launches (kernel boundaries carry the cross-block phi dependency):
//   K0: adj + phi(t=0) -> phiA
//   K1: agg0+g0 (-> stateA) + phi(t=1) -> phiB
//   K2: agg1+g1 (-> stateB) + phi(t=2) -> phiA
//   K3: agg2+g2 -> d_out
// Workspace layout (bytes):
//   lists  @ 0        : 1536*384 u16  (1179648)
//   cnt    @ 1179648  : 1536 int      (6144)
//   phiA   @ 1185792  : 1536*128 f32  (786432)
//   phiB   @ 1972224  : 1536*128 f32  (786432)
//   stateA @ 2758656  : 1536*3 f32    (18432)
//   stateB @ 2777088  : 1536*3 f32    (18432)
// ---------------------------------------------------------------------------

// phi[node][128] = relu(W3^T relu(W2^T relu(W1[3:6]^T s + b1) + b2) + b3)
// One wave per node; lane computes neurons lane and lane+64. H1/H2 are
// per-wave LDS: wave-internal DS ordering makes barriers unnecessary
// (validated bit-exact in round 3).
__device__ __forceinline__ void phi_stage(
    const float* __restrict__ fW1, const float* __restrict__ fb1,
    const float* __restrict__ fW2, const float* __restrict__ fb2,
    const float* __restrict__ fW3, const float* __restrict__ fb3,
    float s0, float s1, float s2, int lane,
    float* __restrict__ H1, float* __restrict__ H2,
    float* __restrict__ phidst /* this node's 128-float row */)
{
    // Layer 1 (effective 3->64; rel slot of the edge input is exactly zero,
    // so rows 0..2 of fW1 are provably unused)
    float v = fb1[lane];
    v = fmaf(s0, fW1[3 * 64 + lane], v);
    v = fmaf(s1, fW1[4 * 64 + lane], v);
    v = fmaf(s2, fW1[5 * 64 + lane], v);
    H1[lane] = fmaxf(v, 0.0f);
    // Layer 2: 64 -> 128
    float a0 = fb2[lane], a1 = fb2[lane + 64];
#pragma unroll 16
    for (int c = 0; c < 64; ++c) {
        const float h = H1[c];
        a0 = fmaf(h, fW2[c * 128 + lane], a0);
        a1 = fmaf(h, fW2[c * 128 + lane + 64], a1);
    }
    H2[lane] = fmaxf(a0, 0.0f);
    H2[lane + 64] = fmaxf(a1, 0.0f);
    // Layer 3: 128 -> 128, final relu
    float c0 = fb3[lane], c1 = fb3[lane + 64];
#pragma unroll 16
    for (int c = 0; c < 128; ++c) {
        const float h = H2[c];
        c0 = fmaf(h, fW3[c * 128 + lane], c0);
        c1 = fmaf(h, fW3[c * 128 + lane + 64], c1);
    }
    phidst[lane] = fmaxf(c0, 0.0f);
    phidst[lane + 64] = fmaxf(c1, 0.0f);
}

// K0: adjacency (ballot-compacted neighbor lists) + phi(t=0).
__global__ __launch_bounds__(256) void adj_phi0_kernel(
    const float* __restrict__ x,
    const float* __restrict__ fW1, const float* __restrict__ fb1,
    const float* __restrict__ fW2, const float* __restrict__ fb2,
    const float* __restrict__ fW3, const float* __restrict__ fb3,
    int* __restrict__ cnt, unsigned short* __restrict__ lists,
    float* __restrict__ phiA)
{
    __shared__ float xs[MNODES * 3];
    __shared__ float work[4][192];
    const int tid = threadIdx.x;
    const int wv = tid >> 6, lane = tid & 63;
    const int node = blockIdx.x * 4 + wv;      // [0,1536)
    const int n = blockIdx.x / 96;             // batch
    const int i = node - n * MNODES;

    for (int idx = tid; idx < MNODES * 3; idx += 256)
        xs[idx] = x[n * MNODES * 3 + idx];
    __syncthreads();

    const float s0 = xs[i * 3], s1 = xs[i * 3 + 1], s2 = xs[i * 3 + 2];
    unsigned short* ml = lists + (size_t)node * MNODES;
    int nc = 0;
#pragma unroll
    for (int rep = 0; rep < 6; ++rep) {
        const int j = rep * 64 + lane;
        float dx = xs[j * 3] - s0;
        float dy = xs[j * 3 + 1] - s1;
        float dz = xs[j * 3 + 2] - s2;
        // match numpy rounding exactly (no fp-contract): (dx*dx + dy*dy) + dz*dz
        float d2 = __fadd_rn(__fadd_rn(__fmul_rn(dx, dx), __fmul_rn(dy, dy)),
                             __fmul_rn(dz, dz));
        const bool a = d2 < RTHRESH;
        const unsigned long long m = __ballot(a);
        if (a) ml[nc + __popcll(m & ((1ull << lane) - 1ull))] = (unsigned short)j;
        nc += (int)__popcll(m);
    }
    if (lane == 0) cnt[node] = nc;

    phi_stage(fW1, fb1, fW2, fb2, fW3, fb3, s0, s1, s2, lane,
              &work[wv][0], &work[wv][64], phiA + (size_t)node * 128);
}

// K1..K3: agg(t)+g(t) (+ phi(t+1) when do_phi). Wave per node.
__global__ __launch_bounds__(256) void step_kernel(
    const float* __restrict__ phisrc, float* __restrict__ phidst,
    const int* __restrict__ cnt, const unsigned short* __restrict__ lists,
    const float* __restrict__ statesrc, float* __restrict__ statedst,
    const float* __restrict__ gW1, const float* __restrict__ gb1,
    const float* __restrict__ gW2, const float* __restrict__ gb2,
    const float* __restrict__ gW3, const float* __restrict__ gb3,
    const float* __restrict__ fW1n, const float* __restrict__ fb1n,
    const float* __restrict__ fW2n, const float* __restrict__ fb2n,
    const float* __restrict__ fW3n, const float* __restrict__ fb3n,
    int do_phi)
{
    __shared__ float work[4][224];  // aggL[128] | h1[64] | h2[32]; phi reuses [0..192)
    const int tid = threadIdx.x;
    const int wv = tid >> 6, lane = tid & 63;
    const int node = __builtin_amdgcn_readfirstlane(blockIdx.x * 4 + wv);
    const int nbase = (blockIdx.x / 96) * MNODES;
    const int nc = cnt[node];
    const unsigned short* ml = lists + (size_t)node * MNODES;
    const float* pb = phisrc + (size_t)nbase * 128;
    float* const aggL = &work[wv][0];
    float* const h1L  = &work[wv][128];
    float* const h2L  = &work[wv][192];

    // agg: max over neighbors. phi >= 0 and non-neighbors contribute 0 in the
    // reference, so init 0 is exact. 8-wide with index clamping: reading the
    // last neighbor multiple times is harmless under max (no serial cleanup;
    // 16 outstanding 256B loads). nc >= 1 always (self-edge: d2 = 0 < R).
    float m[8], p[8];
#pragma unroll
    for (int k = 0; k < 8; ++k) { m[k] = 0.0f; p[k] = 0.0f; }
    const int last = nc - 1;
    for (int jj = 0; jj < nc; jj += 8) {
        const float* r[8];
#pragma unroll
        for (int k = 0; k < 8; ++k) {
            const int jc = jj + k;
            const int j = ml[jc < last ? jc : last];
            r[k] = pb + (size_t)j * 128;
        }
#pragma unroll
        for (int k = 0; k < 8; ++k) {
            m[k] = fmaxf(m[k], r[k][lane]);
            p[k] = fmaxf(p[k], r[k][lane + 64]);
        }
    }
    aggL[lane] = fmaxf(fmaxf(fmaxf(m[0], m[1]), fmaxf(m[2], m[3])),
                       fmaxf(fmaxf(m[4], m[5]), fmaxf(m[6], m[7])));
    aggL[lane + 64] = fmaxf(fmaxf(fmaxf(p[0], p[1]), fmaxf(p[2], p[3])),
                            fmaxf(fmaxf(p[4], p[5]), fmaxf(p[6], p[7])));

    // g1: 128 -> 64
    float h = gb1[lane];
#pragma unroll 16
    for (int c = 0; c < 128; ++c) h = fmaf(aggL[c], gW1[c * 64 + lane], h);
    h1L[lane] = fmaxf(h, 0.0f);
    // g2: 64 -> 32
    if (lane < 32) {
        float v2 = gb2[lane];
#pragma unroll 16
        for (int k = 0; k < 64; ++k) v2 = fmaf(h1L[k], gW2[k * 32 + lane], v2);
        h2L[lane] = fmaxf(v2, 0.0f);
    }
    // g3: 32 -> 3, final relu, residual
    float sv = 0.0f;
    if (lane < 3) sv = statesrc[node * 3 + lane];
    float ns = 0.0f;
    if (lane < 3) {
        float v3 = gb3[lane];
#pragma unroll
        for (int q = 0; q < 32; ++q) v3 = fmaf(h2L[q], gW3[q * 3 + lane], v3);
        ns = fmaxf(v3, 0.0f) + sv;
        statedst[node * 3 + lane] = ns;
    }
    if (do_phi) {
        const float s0 = __shfl(ns, 0), s1 = __shfl(ns, 1), s2 = __shfl(ns, 2);
        phi_stage(fW1n, fb1n, fW2n, fb2n, fW3n, fb3n, s0, s1, s2, lane,
                  &work[wv][0], &work[wv][64], phidst + (size_t)node * 128);
    }
}

extern "C" void kernel_launch(void* const* d_in, const int* in_sizes, int n_in,
                              void* d_out, int out_size, void* d_ws, size_t ws_size,
                              hipStream_t stream) {
    const float* x   = (const float*)d_in[0];
    // d_in[1..6] = hW1..hb3 : provably unused (delta MLP receives exact zeros)
    const float* fW1 = (const float*)d_in[7];
    const float* fb1 = (const float*)d_in[8];
    const float* fW2 = (const float*)d_in[9];
    const float* fb2 = (const float*)d_in[10];
    const float* fW3 = (const float*)d_in[11];
    const float* fb3 = (const float*)d_in[12];
    const float* gW1 = (const float*)d_in[13];
    const float* gb1 = (const float*)d_in[14];
    const float* gW2 = (const float*)d_in[15];
    const float* gb2 = (const float*)d_in[16];
    const float* gW3 = (const float*)d_in[17];
    const float* gb3 = (const float*)d_in[18];

    char* ws = (char*)d_ws;
    unsigned short* lists = (unsigned short*)(ws + 0);
    int* cnt              = (int*)(ws + 1179648);
    float* phiA           = (float*)(ws + 1185792);
    float* phiB           = (float*)(ws + 1972224);
    float* stateA         = (float*)(ws + 2758656);
    float* stateB         = (float*)(ws + 2777088);
    float* outp           = (float*)d_out;

    // K0: adj + phi0 -> phiA
    adj_phi0_kernel<<<384, 256, 0, stream>>>(x, fW1, fb1, fW2, fb2, fW3, fb3,
                                             cnt, lists, phiA);
    // K1: agg0+g0 (x -> stateA) + phi1 -> phiB
    step_kernel<<<384, 256, 0, stream>>>(phiA, phiB, cnt, lists, x, stateA,
                                         gW1, gb1, gW2, gb2, gW3, gb3,
                                         fW1 + 384, fb1 + 64, fW2 + 8192, fb2 + 128,
                                         fW3 + 16384, fb3 + 128, 1);
    // K2: agg1+g1 (stateA -> stateB) + phi2 -> phiA
    step_kernel<<<384, 256, 0, stream>>>(phiB, phiA, cnt, lists, stateA, stateB,
                                         gW1 + 8192, gb1 + 64, gW2 + 2048, gb2 + 32,
                                         gW3 + 96, gb3 + 3,
                                         fW1 + 768, fb1 + 128, fW2 + 16384, fb2 + 256,
                                         fW3 + 32768, fb3 + 256, 1);
    // K3: agg2+g2 (stateB -> out)
    step_kernel<<<384, 256, 0, stream>>>(phiA, phiB, cnt, lists, stateB, outp,
                                         gW1 + 16384, gb1 + 128, gW2 + 4096, gb2 + 64,
                                         gW3 + 192, gb3 + 6,
                                         fW1, fb1, fW2, fb2, fW3, fb3, 0);
}